// Round 17
// baseline (31073.599 us; speedup 1.0000x reference)
//
#include <hip/hip_runtime.h>
#include <hip/hip_bf16.h>

// LSTM: B=64, S=512, D=512, H=1024, L=2, O=256
// Persistent kernel, BARRIER-FREE split-K, direct-to-VGPR A-fragments:
//   - 256 WGs x 512 thr (1/CU). WG = 8 h-cols; 8 waves = 8 K-slices (disjoint).
//   - Each lane loads its own MFMA A-fragments (16B units) straight from re-tiled
//     global slabs (windowed volatile-asm loads, counted vmcnt). No LDS staging,
//     no per-chunk barriers; 2 syncthreads/phase (Pf reduction + store/arrive).
//   - Per-WAVE dependency waits: x-waves wait nothing, own-layer-h waves wait own
//     group, cross-layer waves wait producer group -> detect latency overlaps
//     with own-half compute.
//   - h slabs tiled [kstep32][row64][q4][16B]; h coherence via sc0 sc1 (IF).
//   - Weights VGPR-resident (KST*2 frags/wave). L0: WGs 0-127, L1: WGs 128-255.

namespace {
constexpr int Bn = 64, Sn = 512, Dn = 512, Hn = 1024, On = 256;
constexpr int BH = Bn * Hn;        // 65536
}

typedef unsigned short u16;
typedef unsigned int u32;
typedef float f32x4 __attribute__((ext_vector_type(4)));
typedef short s16x8 __attribute__((ext_vector_type(8)));

__device__ __forceinline__ u16 f2bf(float f) {
    unsigned int u = __float_as_uint(f);
    unsigned int r = (u + 0x7fffu + ((u >> 16) & 1u)) >> 16;
    return (u16)r;
}
__device__ __forceinline__ float bf2f(u16 b) {
    return __uint_as_float(((unsigned int)b) << 16);
}
__device__ __forceinline__ float sigmf(float x) { return 1.0f / (1.0f + __expf(-x)); }

// ---- coherent / pinned access primitives ----
__device__ __forceinline__ void stg_coh16(u16* p, u32 v) {
    asm volatile("global_store_short %0, %1, off sc0 sc1" :: "v"(p), "v"(v) : "memory");
}
__device__ __forceinline__ u32 ldg_coh_u32(const u32* p) {
    u32 r;
    asm volatile("global_load_dword %0, %1, off sc0 sc1" : "=&v"(r) : "v"(p) : "memory");
    return r;
}
__device__ __forceinline__ s16x8 ldg_coh(const u16* p) {
    s16x8 r;
    asm volatile("global_load_dwordx4 %0, %1, off sc0 sc1" : "=&v"(r) : "v"(p) : "memory");
    return r;
}
__device__ __forceinline__ s16x8 ldg_pin(const u16* p) {
    s16x8 r;
    asm volatile("global_load_dwordx4 %0, %1, off" : "=&v"(r) : "v"(p) : "memory");
    return r;
}
__device__ __forceinline__ void waitvm0() {
    asm volatile("s_waitcnt vmcnt(0)" ::: "memory");
    __builtin_amdgcn_sched_barrier(0);
}

template <int I> struct IC { static constexpr int v = I; };
template <int N, int I = 0, typename F>
__device__ __forceinline__ void sfor(F&& f) {
    if constexpr (I < N) { f(IC<I>{}); sfor<N, I + 1, F>(static_cast<F&&>(f)); }
}

template <int N> __device__ __forceinline__ void waitvmN() {
    static_assert(N >= 0 && N <= 16, "unexpected vmcnt");
    if constexpr (N == 0)  asm volatile("s_waitcnt vmcnt(0)" ::: "memory");
    else if constexpr (N == 4)  asm volatile("s_waitcnt vmcnt(4)" ::: "memory");
    else if constexpr (N == 8)  asm volatile("s_waitcnt vmcnt(8)" ::: "memory");
    else if constexpr (N == 12) asm volatile("s_waitcnt vmcnt(12)" ::: "memory");
    else if constexpr (N == 16) asm volatile("s_waitcnt vmcnt(16)" ::: "memory");
    __builtin_amdgcn_sched_barrier(0);
}

// ---------------- prep: re-tiled packs ----------------
// h slab unit layout: [ks2(32k-step)][row 64][q 4][16B]; unit (ks2,r,q) holds cols
// ks2*32+q*8 .. +8 of row r. x-pack per t: same tiling, 16 ksteps (k<512).
// Wpk: ((((wgl*8+wid)*KST + j)*2 + gt)*64 + lane)*8 + jj ; row = (2gt+(pr>>3))*1024
// + wgl*8 + (pr&7), k = (wid*KST+j)*32 + lh*8 + jj.
__global__ void prep_kernel(const float* __restrict__ Wx0, const float* __restrict__ Wh0,
                            const float* __restrict__ bx0, const float* __restrict__ bh0,
                            const float* __restrict__ Wx1, const float* __restrict__ Wh1,
                            const float* __restrict__ bx1, const float* __restrict__ bh1,
                            const float* __restrict__ h0in, const float* __restrict__ x,
                            u16* __restrict__ Wpk0, u16* __restrict__ Wpk1,
                            u16* __restrict__ xpk, float* __restrict__ bcomb,
                            u16* __restrict__ h0buf, u16* __restrict__ h1buf,
                            u32* __restrict__ cnt) {
    const long long idx = (long long)blockIdx.x * 256 + threadIdx.x;
    const long long stride = (long long)gridDim.x * 256;
    if (idx < 16) cnt[idx * 16] = 0u;   // cnt0: slots 0-7, cnt1: slots 8-15

    // Wpk0: KST=6, KX=512
    for (long long i = idx; i < 6291456LL; i += stride) {
        const int jj = (int)(i & 7);
        const int lane = (int)((i >> 3) & 63);
        const int gt = (int)((i >> 9) & 1);
        const int rem = (int)(i >> 10);
        const int j = rem % 6;
        const int rem2 = rem / 6;
        const int wid = rem2 & 7, wgl = rem2 >> 3;
        const int pr = lane & 15, lh = lane >> 4;
        const int row = (2 * gt + (pr >> 3)) * 1024 + wgl * 8 + (pr & 7);
        const int k = (wid * 6 + j) * 32 + lh * 8 + jj;
        const float v = (k < 512) ? Wx0[(size_t)row * 512 + k] : Wh0[(size_t)row * 1024 + (k - 512)];
        Wpk0[i] = f2bf(v);
    }
    // Wpk1: KST=8, KX=1024
    for (long long i = idx; i < 8388608LL; i += stride) {
        const int jj = (int)(i & 7);
        const int lane = (int)((i >> 3) & 63);
        const int gt = (int)((i >> 9) & 1);
        const int rem = (int)(i >> 10);
        const int j = rem & 7;
        const int rem2 = rem >> 3;
        const int wid = rem2 & 7, wgl = rem2 >> 3;
        const int pr = lane & 15, lh = lane >> 4;
        const int row = (2 * gt + (pr >> 3)) * 1024 + wgl * 8 + (pr & 7);
        const int k = (wid * 8 + j) * 32 + lh * 8 + jj;
        const float v = (k < 1024) ? Wx1[(size_t)row * 1024 + k] : Wh1[(size_t)row * 1024 + (k - 1024)];
        Wpk1[i] = f2bf(v);
    }
    // x-pack: unit i: q=i&3, r=(i>>2)&63, ks2=(i>>8)&15, t=i>>12 ; linear dst
    for (long long i = idx; i < 2097152LL; i += stride) {
        const int q = (int)(i & 3);
        const int r = (int)((i >> 2) & 63);
        const int ks2 = (int)((i >> 8) & 15);
        const int t = (int)(i >> 12);
        const float* sp = x + ((size_t)r * Sn + t) * Dn + ks2 * 32 + q * 8;
        s16x8 v;
#pragma unroll
        for (int jj = 0; jj < 8; ++jj) v[jj] = (short)f2bf(sp[jj]);
        *(s16x8*)&xpk[i * 8] = v;
    }
    for (long long i = idx; i < 4096; i += stride) {
        bcomb[i] = bx0[i] + bh0[i];
        bcomb[4096 + i] = bx1[i] + bh1[i];
    }
    // initial h slabs (new unit layout): L0 reads h0 slab 3 at p=0; L1 reads h1 slab 1.
    for (long long i = idx; i < 8192; i += stride) {
        const int q = (int)(i & 3);
        const int r = (int)((i >> 2) & 63);
        const int ks2 = (int)(i >> 8);
        const int k0 = ks2 * 32 + q * 8;
        s16x8 v0, v1;
#pragma unroll
        for (int jj = 0; jj < 8; ++jj) {
            v0[jj] = (short)f2bf(h0in[(size_t)r * Hn + k0 + jj]);
            v1[jj] = (short)f2bf(h0in[(size_t)BH + r * Hn + k0 + jj]);
        }
        *(s16x8*)&h0buf[3 * 65536 + i * 8] = v0;
        *(s16x8*)&h1buf[1 * 65536 + i * 8] = v1;
    }
}

// ---------------- per-WAVE bounded wait on one counter group ----------------
__device__ __forceinline__ void wwait(const u32* base8, u32 tgt, int& dead) {
    if (dead) return;
    int guard = 0;
    for (;;) {
        u32 s = 0;
#pragma unroll
        for (int k = 0; k < 8; ++k) s += ldg_coh_u32(base8 + k * 16);
        waitvm0();
        if (s >= tgt) return;
        __builtin_amdgcn_s_sleep(1);
        if (++guard > (1 << 12)) { dead = 1; return; }
    }
}

__device__ __forceinline__ f32x4 mfma(s16x8 a, s16x8 b, f32x4 c) {
    return __builtin_amdgcn_mfma_f32_16x16x32_bf16(a, b, c, 0, 0, 0);
}

// ---------------- per-layer persistent loop ----------------
// KST ksteps(32k) per wave (L0:6, L1:8). WG = 8 cols; thread = (m=lane, c8=wid).
template <int KST, int LAYER>
__device__ __forceinline__ void run_layer(const u16* __restrict__ xpk,
                                          const u16* __restrict__ Wpk,
                                          const float* __restrict__ bias,
                                          const float* __restrict__ c0in,
                                          u16* h0buf, u16* h1buf, u16* h1fin,
                                          u32* cnt, int wgl, char* smem) {
    constexpr int W = 5;                       // load window (kstep groups in flight)
    const int tid = threadIdx.x;
    const int wid = tid >> 6, lane = tid & 63;
    const int ln15 = lane & 15, lhi = lane >> 4;
    const int col0 = wgl * 8;
    float* Pf = (float*)smem;                  // [8 waves][32 grow][65] f32
    u32* c0base = cnt;
    u32* c1base = cnt + 128;
    u32* slotp = cnt + (LAYER == 0 ? 0 : 128) + (wgl & 7) * 16;
    int dead = 0;

    // resident weights: KST*2 fragments
    s16x8 wB[KST][2];
    const u16* wbase = Wpk + ((size_t)(wgl * 8 + wid) * KST) * 2 * 512 + lane * 8;
    sfor<KST>([&](auto jc) {
        wB[jc.v][0] = ldg_pin(wbase + (size_t)(jc.v * 2 + 0) * 512);
        wB[jc.v][1] = ldg_pin(wbase + (size_t)(jc.v * 2 + 1) * 512);
    });
    waitvm0();

    const int loff = ln15 * 32 + lhi * 8;      // per-lane u16 offset within a kstep panel
    const int cg = col0 + wid;                 // this thread's h column
    const int stoff = (cg >> 5) * 2048 + ((cg >> 3) & 3) * 8 + (cg & 7);  // + m*32
    float bR[4];
#pragma unroll
    for (int g = 0; g < 4; ++g) bR[g] = bias[g * 1024 + cg];
    float cr = c0in[(size_t)lane * 1024 + cg];

    s16x8 af[W][4];
    f32x4 acc[4][2];

    for (int p = 0; p < Sn; ++p) {
        // ---- per-wave dependency waits (decoupled; x-waves wait nothing)
        if constexpr (LAYER == 0) {
            if (wid >= 2 && p >= 1) wwait(c0base, 128u * (u32)p, dead);       // h0[p-1]
            if (wid == 0 && p >= 4) wwait(c1base, 128u * (u32)(p - 3), dead); // slab recycle
        } else {
            if (wid < 4) wwait(c0base, 128u * (u32)(p + 1), dead);            // h0[p]
            else if (p >= 1) wwait(c1base, 128u * (u32)p, dead);              // h1[p-1]
        }

        const u16* xsl = (LAYER == 0) ? xpk + (size_t)p * 32768 : nullptr;
        const u16* h0r = h0buf + (size_t)((LAYER == 0 ? (p - 1) : p) & 3) * 65536;
        const u16* h1r = (LAYER == 1) ? h1buf + (size_t)((p - 1) & 1) * 65536 : nullptr;

        auto issueG = [&](auto jc) {
            constexpr int j = jc.v;
            const int g2 = wid * KST + j;
            const u16* bp; bool coh;
            if constexpr (LAYER == 0) {
                if (g2 < 16) { bp = xsl + g2 * 2048 + loff; coh = false; }
                else         { bp = h0r + (g2 - 16) * 2048 + loff; coh = true; }
            } else {
                if (g2 < 32) { bp = h0r + g2 * 2048 + loff; coh = true; }
                else         { bp = h1r + (g2 - 32) * 2048 + loff; coh = true; }
            }
#pragma unroll
            for (int mi = 0; mi < 4; ++mi)
                af[j % W][mi] = coh ? ldg_coh(bp + mi * 512) : ldg_pin(bp + mi * 512);
        };

        constexpr int PW = (W < KST) ? W : KST;
        sfor<PW>([&](auto k) { issueG(k); });

#pragma unroll
        for (int mi = 0; mi < 4; ++mi) {
            acc[mi][0] = f32x4{0.f, 0.f, 0.f, 0.f};
            acc[mi][1] = f32x4{0.f, 0.f, 0.f, 0.f};
        }

        sfor<KST>([&](auto jc) {
            constexpr int j = jc.v;
            constexpr int R = (W - 1 < KST - 1 - j) ? (W - 1) : (KST - 1 - j);
            waitvmN<4 * R>();                   // group j's 4 fragments arrived
#pragma unroll
            for (int mi = 0; mi < 4; ++mi) {
                acc[mi][0] = mfma(af[j % W][mi], wB[j][0], acc[mi][0]);
                acc[mi][1] = mfma(af[j % W][mi], wB[j][1], acc[mi][1]);
            }
            __builtin_amdgcn_sched_barrier(0);  // keep ring-slot reuse after consume
            if constexpr (j + W < KST) issueG(IC<j + W>{});
        });

        // ---- cross-wave reduction: each wave writes its partials (no barrier needed
        // before: previous phase's epilogue syncthreads ordered all Pf readers).
#pragma unroll
        for (int mi = 0; mi < 4; ++mi)
#pragma unroll
            for (int gt = 0; gt < 2; ++gt)
#pragma unroll
                for (int r = 0; r < 4; ++r) {
                    const int grow = (2 * gt + (ln15 >> 3)) * 8 + (ln15 & 7);
                    const int m = mi * 16 + lhi * 4 + r;
                    Pf[(wid * 32 + grow) * 65 + m] = acc[mi][gt][r];
                }
        __syncthreads();

        // ---- fused cell update: thread owns (m=lane, col cg)
        float sg[4];
#pragma unroll
        for (int g = 0; g < 4; ++g) sg[g] = bR[g];
#pragma unroll
        for (int w8 = 0; w8 < 8; ++w8)
#pragma unroll
            for (int g = 0; g < 4; ++g)
                sg[g] += Pf[(w8 * 32 + g * 8 + wid) * 65 + lane];
        const float iv = sigmf(sg[0]), fv = sigmf(sg[1]);
        const float gv = tanhf(sg[2]), ov = sigmf(sg[3]);
        cr = fv * cr + iv * gv;
        const u16 hb = f2bf(ov * tanhf(cr));

        if (LAYER == 1 && p == Sn - 1) {
            h1fin[(size_t)lane * Hn + cg] = hb;            // plain layout for FC
        } else {
            u16* hw = (LAYER == 0) ? h0buf + (size_t)(p & 3) * 65536
                                   : h1buf + (size_t)(p & 1) * 65536;
            stg_coh16(hw + stoff + lane * 32, (u32)hb);
        }
        waitvm0();            // own store acked at coherence point
        __syncthreads();      // all waves' stores acked
        if (tid == 0) atomicAdd(slotp, 1u);
    }
    waitvm0();
}

__global__ __attribute__((amdgpu_flat_work_group_size(512, 512)))
void lstm_persist(const u16* __restrict__ xpk,
                  const u16* __restrict__ Wpk0,
                  const u16* __restrict__ Wpk1,
                  const float* __restrict__ bias,
                  const float* __restrict__ c0in,
                  u16* h0buf, u16* h1buf, u16* h1fin, u32* cnt) {
    // ~66.5 KB used (Pf); padded to 90 KB so exactly 1 WG/CU -> 256-VGPR budget.
    __shared__ __align__(16) char smem[92160];
    if (blockIdx.x < 128)
        run_layer<6, 0>(xpk, Wpk0, bias, c0in, h0buf, h1buf, h1fin, cnt, blockIdx.x, smem);
    else
        run_layer<8, 1>(xpk, Wpk1, bias + 4096, c0in + BH, h0buf, h1buf, h1fin, cnt,
                        blockIdx.x - 128, smem);
}

// ---------------- final FC + sigmoid ----------------
__global__ __launch_bounds__(256) void fc_out(const u16* __restrict__ h1,
                                              const float* __restrict__ fcW,
                                              const float* __restrict__ fcb,
                                              float* __restrict__ out) {
    const int b = blockIdx.x;  // 64
    __shared__ float hs[Hn];
    for (int k = threadIdx.x; k < Hn; k += 256) hs[k] = bf2f(h1[(size_t)b * Hn + k]);
    __syncthreads();
    const int o = threadIdx.x;  // 256
    float acc = fcb[o];
    const float4* wr = (const float4*)(fcW + (size_t)o * Hn);
    const float4* hv = (const float4*)hs;
#pragma unroll 8
    for (int k4 = 0; k4 < Hn / 4; ++k4) {
        const float4 w = wr[k4];
        const float4 h = hv[k4];
        acc += w.x * h.x + w.y * h.y + w.z * h.z + w.w * h.w;
    }
    out[(size_t)b * On + o] = sigmf(acc);
}

extern "C" void kernel_launch(void* const* d_in, const int* in_sizes, int n_in,
                              void* d_out, int out_size, void* d_ws, size_t ws_size,
                              hipStream_t stream) {
    (void)in_sizes; (void)n_in; (void)out_size; (void)ws_size;
    const float* x   = (const float*)d_in[0];
    const float* h0i = (const float*)d_in[1];
    const float* c0i = (const float*)d_in[2];
    const float* Wx0 = (const float*)d_in[3];
    const float* Wh0 = (const float*)d_in[4];
    const float* bx0 = (const float*)d_in[5];
    const float* bh0 = (const float*)d_in[6];
    const float* Wx1 = (const float*)d_in[7];
    const float* Wh1 = (const float*)d_in[8];
    const float* bx1 = (const float*)d_in[9];
    const float* bh1 = (const float*)d_in[10];
    const float* fcW = (const float*)d_in[11];
    const float* fcb = (const float*)d_in[12];
    float* out = (float*)d_out;

    char* ws = (char*)d_ws;
    u16* Wpk0   = (u16*)(ws + 0);            // 12,582,912 B
    u16* Wpk1   = (u16*)(ws + 12582912);     // 16,777,216 B
    u16* xpk    = (u16*)(ws + 29360128);     // 33,554,432 B  re-tiled bf16
    float* bias = (float*)(ws + 62914560);   // 32,768 B
    u16* h0buf  = (u16*)(ws + 62947328);     // 524,288 B (4 tiled slabs)
    u16* h1buf  = (u16*)(ws + 63471616);     // 262,144 B (2 tiled slabs)
    u16* h1fin  = (u16*)(ws + 63733760);     // 131,072 B (plain, for FC)
    u32* cnt    = (u32*)(ws + 63864832);     // 1,024 B (16 split counters)

    prep_kernel<<<2048, 256, 0, stream>>>(Wx0, Wh0, bx0, bh0, Wx1, Wh1, bx1, bh1,
                                          h0i, x, Wpk0, Wpk1, xpk, bias, h0buf, h1buf, cnt);

    lstm_persist<<<256, 512, 0, stream>>>(xpk, Wpk0, Wpk1, bias, c0i, h0buf, h1buf, h1fin, cnt);

    fc_out<<<64, 256, 0, stream>>>(h1fin, fcW, fcb, out);
}

// Round 18
// 5062.444 us; speedup vs baseline: 6.1381x; 6.1381x over previous
//
#include <hip/hip_runtime.h>
#include <hip/hip_bf16.h>

// LSTM: B=64, S=512, D=512, H=1024, L=2, O=256
// Persistent kernel, DECOUPLED layer groups (no global barrier):
//   - L0 (WGs 0-63) and L1 (WGs 64-127) each have their own 64-arrival barrier.
//   - 4 rotating h0 slabs let L0 run up to 3 phases ahead; L1 (critical path)
//     finds its dependencies already satisfied -> pays only its own group barrier.
//   - 16 waves/WG; weights VGPR-resident (NC frags/wave, loaded once).
//   - A-panel staged via global_load_lds into an 8-slot LDS ring, lookahead 7.
//   - h slabs PRE-SWIZZLED; h coherence via sc0 sc1 (IF); monotone counters.
// Best-validated configuration (round 15: 4.917 ms). The ~9.6us/phase clock is the
// per-CU coherent-read transaction wall (~26 GB/s/CU) on the B=64 K-panel broadcast
// x 512 sequential steps — measured invariant across weight-residency, barrier,
// cache-policy and load-granularity variants (rounds 10-17).

namespace {
constexpr int Bn = 64, Sn = 512, Dn = 512, Hn = 1024, On = 256;
constexpr int BH = Bn * Hn;        // 65536
constexpr int SLAB = BH * 2;       // 131072 bytes per h slab (bf16)
}

typedef unsigned short u16;
typedef unsigned int u32;
typedef float f32x4 __attribute__((ext_vector_type(4)));
typedef short s16x8 __attribute__((ext_vector_type(8)));
typedef unsigned int u32x4 __attribute__((ext_vector_type(4)));

__device__ __forceinline__ u16 f2bf(float f) {
    unsigned int u = __float_as_uint(f);
    unsigned int r = (u + 0x7fffu + ((u >> 16) & 1u)) >> 16;
    return (u16)r;
}
__device__ __forceinline__ float bf2f(u16 b) {
    return __uint_as_float(((unsigned int)b) << 16);
}
__device__ __forceinline__ float sigmf(float x) { return 1.0f / (1.0f + __expf(-x)); }

// ---- coherent primitives ----
__device__ __forceinline__ void stg_coh128(u16* p, u32x4 v) {
    asm volatile("global_store_dwordx4 %0, %1, off sc0 sc1" :: "v"(p), "v"(v) : "memory");
}
__device__ __forceinline__ u32 ldg_coh_u32(const u32* p) {
    u32 r;
    asm volatile("global_load_dword %0, %1, off sc0 sc1" : "=&v"(r) : "v"(p) : "memory");
    return r;
}
// plain 16B load as volatile asm (single VMEM instr; cannot be rematerialized)
__device__ __forceinline__ s16x8 ldg_pin(const u16* p) {
    s16x8 r;
    asm volatile("global_load_dwordx4 %0, %1, off" : "=&v"(r) : "v"(p) : "memory");
    return r;
}
__device__ __forceinline__ void waitvm0() {
    asm volatile("s_waitcnt vmcnt(0)" ::: "memory");
    __builtin_amdgcn_sched_barrier(0);
}

// ---- DMA global->LDS (16B/lane). dst wave-uniform; lane*16 implicit.
__device__ __forceinline__ void dmaA(const void* src, void* dst) {
    __builtin_amdgcn_global_load_lds((const __attribute__((address_space(1))) void*)src,
                                     (__attribute__((address_space(3))) void*)dst, 16, 0, 0);
}
__device__ __forceinline__ void dmaAcoh(const void* src, void* dst) {
    // SC0|SC1 = 17: IF-coherent read (bypass stale L2)
    __builtin_amdgcn_global_load_lds((const __attribute__((address_space(1))) void*)src,
                                     (__attribute__((address_space(3))) void*)dst, 16, 0, 17);
}

template <int I> struct IC { static constexpr int v = I; };
template <int N, int I = 0, typename F>
__device__ __forceinline__ void sfor(F&& f) {
    if constexpr (I < N) { f(IC<I>{}); sfor<N, I + 1, F>(static_cast<F&&>(f)); }
}

template <int N> __device__ __forceinline__ void waitvmN() {
    static_assert(N >= 0 && N <= 8, "unexpected vmcnt");
    if constexpr (N == 0)  asm volatile("s_waitcnt vmcnt(0)" ::: "memory");
    else if constexpr (N == 1)  asm volatile("s_waitcnt vmcnt(1)" ::: "memory");
    else if constexpr (N == 2)  asm volatile("s_waitcnt vmcnt(2)" ::: "memory");
    else if constexpr (N == 3)  asm volatile("s_waitcnt vmcnt(3)" ::: "memory");
    else if constexpr (N == 4)  asm volatile("s_waitcnt vmcnt(4)" ::: "memory");
    else if constexpr (N == 5)  asm volatile("s_waitcnt vmcnt(5)" ::: "memory");
    else if constexpr (N == 6)  asm volatile("s_waitcnt vmcnt(6)" ::: "memory");
    else if constexpr (N == 7)  asm volatile("s_waitcnt vmcnt(7)" ::: "memory");
    else if constexpr (N == 8)  asm volatile("s_waitcnt vmcnt(8)" ::: "memory");
    __builtin_amdgcn_sched_barrier(0);
}

// Pf bank-swizzled index: row-major [256][64] f32 with XOR on the m index.
__device__ __forceinline__ int PFI(int row, int m) {
    return row * 64 + (m ^ ((row & 7) << 2));
}

// ---------------- prep ----------------
__global__ void prep_kernel(const float* __restrict__ Wx0, const float* __restrict__ Wh0,
                            const float* __restrict__ bx0, const float* __restrict__ bh0,
                            const float* __restrict__ Wx1, const float* __restrict__ Wh1,
                            const float* __restrict__ bx1, const float* __restrict__ bh1,
                            const float* __restrict__ h0in, const float* __restrict__ x,
                            u16* __restrict__ Wpk0, u16* __restrict__ Wpk1,
                            u16* __restrict__ xpk, float* __restrict__ bcomb,
                            u16* __restrict__ h0buf, u16* __restrict__ h1buf,
                            u32* __restrict__ cnt) {
    const long long idx = (long long)blockIdx.x * 256 + threadIdx.x;
    const long long stride = (long long)gridDim.x * 256;
    if (idx < 16) cnt[idx * 16] = 0u;   // cnt0: slots 0-7, cnt1: slots 8-15 (64B apart)

    for (long long i = idx; i < 128LL * 4 * 24 * 512; i += stride) {
        const int j = (int)(i & 7);
        const int lane = (int)((i >> 3) & 63);
        const int f = (int)(i >> 9);
        const int nt = f & 1;
        const int q = f >> 1;
        const int c = q % 12, r = q / 12;
        const int wv = r & 3, wg = r >> 2;
        const int pr = lane & 15, lh = lane >> 4;
        const int row = (nt * 2 + (pr >> 3)) * 1024 + wg * 8 + (pr & 7);
        const int k = (c * 4 + wv) * 32 + lh * 8 + j;
        const float v = (k < 512) ? Wx0[(size_t)row * 512 + k] : Wh0[(size_t)row * 1024 + (k - 512)];
        Wpk0[i] = f2bf(v);
    }
    for (long long i = idx; i < 128LL * 4 * 32 * 512; i += stride) {
        const int j = (int)(i & 7);
        const int lane = (int)((i >> 3) & 63);
        const int f = (int)(i >> 9);
        const int nt = f & 1;
        const int q = f >> 1;
        const int c = q & 15, r = q >> 4;
        const int wv = r & 3, wg = r >> 2;
        const int pr = lane & 15, lh = lane >> 4;
        const int row = (nt * 2 + (pr >> 3)) * 1024 + wg * 8 + (pr & 7);
        const int k = (c * 4 + wv) * 32 + lh * 8 + j;
        const float v = (k < 1024) ? Wx1[(size_t)row * 1024 + k] : Wh1[(size_t)row * 1024 + (k - 1024)];
        Wpk1[i] = f2bf(v);
    }
    // x -> bf16 [t][b][d]
    for (long long bi = idx; bi < 512LL * 64 * 64; bi += stride) {
        const int db = (int)(bi & 63);
        const int r = (int)((bi >> 6) & 63);
        const int t = (int)(bi >> 12);
        const float* sp = x + ((size_t)r * Sn + t) * Dn + db * 8;
        const float4 a = *(const float4*)sp;
        const float4 b = *(const float4*)(sp + 4);
        s16x8 v;
        v[0] = (short)f2bf(a.x); v[1] = (short)f2bf(a.y); v[2] = (short)f2bf(a.z); v[3] = (short)f2bf(a.w);
        v[4] = (short)f2bf(b.x); v[5] = (short)f2bf(b.y); v[6] = (short)f2bf(b.z); v[7] = (short)f2bf(b.w);
        *(s16x8*)&xpk[bi * 8] = v;
    }
    for (long long i = idx; i < 4096; i += stride) {
        bcomb[i] = bx0[i] + bh0[i];
        bcomb[4096 + i] = bx1[i] + bh1[i];
    }
    // initial h states (PRE-SWIZZLED): L0 phase 0 reads h0 slab (-1)&3 = 3;
    // L1 phase 0 reads h1 slab (-1)&1 = 1.
    for (long long bi = idx; bi < 8192; bi += stride) {
        const int ck = (int)(bi >> 10), w = (int)(bi & 1023);
        const int r = w >> 4, b = w & 15;
        const int cbl = b ^ (r & 7);
        const int k = ck * 128 + cbl * 8;
        s16x8 v0, v1;
#pragma unroll
        for (int j = 0; j < 8; ++j) {
            v0[j] = (short)f2bf(h0in[(size_t)r * Hn + k + j]);
            v1[j] = (short)f2bf(h0in[(size_t)BH + r * Hn + k + j]);
        }
        *(s16x8*)&h0buf[3 * 65536 + bi * 8] = v0;
        *(s16x8*)&h1buf[1 * 65536 + bi * 8] = v1;
    }
}

// ---------------- dual-counter wait (group-decoupled, bounded) ----------------
__device__ __forceinline__ void waitcnts(u32* cbase, u32 tgt0, u32 tgt1, int& dead) {
    __syncthreads();
    if (threadIdx.x == 0 && !dead) {
        int guard = 0;
        for (;;) {
            u32 a0 = ldg_coh_u32(cbase + 0 * 16),  a1 = ldg_coh_u32(cbase + 1 * 16);
            u32 a2 = ldg_coh_u32(cbase + 2 * 16),  a3 = ldg_coh_u32(cbase + 3 * 16);
            u32 a4 = ldg_coh_u32(cbase + 4 * 16),  a5 = ldg_coh_u32(cbase + 5 * 16);
            u32 a6 = ldg_coh_u32(cbase + 6 * 16),  a7 = ldg_coh_u32(cbase + 7 * 16);
            u32 b0 = ldg_coh_u32(cbase + 8 * 16),  b1 = ldg_coh_u32(cbase + 9 * 16);
            u32 b2 = ldg_coh_u32(cbase + 10 * 16), b3 = ldg_coh_u32(cbase + 11 * 16);
            u32 b4 = ldg_coh_u32(cbase + 12 * 16), b5 = ldg_coh_u32(cbase + 13 * 16);
            u32 b6 = ldg_coh_u32(cbase + 14 * 16), b7 = ldg_coh_u32(cbase + 15 * 16);
            waitvm0();
            const u32 s0 = a0 + a1 + a2 + a3 + a4 + a5 + a6 + a7;
            const u32 s1 = b0 + b1 + b2 + b3 + b4 + b5 + b6 + b7;
            if (s0 >= tgt0 && s1 >= tgt1) break;
            __builtin_amdgcn_s_sleep(1);
            if (++guard > (1 << 12)) { dead = 1; break; }
        }
    }
    __syncthreads();
}
// arrival: all stores acked -> one atomic into this group's split slot
__device__ __forceinline__ void arrive(u32* slotp, int& dead) {
    waitvm0();
    __syncthreads();
    if (threadIdx.x == 0 && !dead) atomicAdd(slotp, 1u);
}

// ---------------- per-layer persistent loop (decoupled groups) ----------------
// NC chunks of 128 k (L0:12, L1:16); XC = chunks from first source (L0: xpk 4; L1: h0 8).
// 16 waves: wid = cg*8 + nt*4 + ks. Weights: NC frags resident in VGPRs.
template <int NC, int XC, int LAYER>
__device__ __forceinline__ void run_layer(const u16* __restrict__ xpk,
                                          const u16* __restrict__ Wpk,
                                          const float* __restrict__ bias,
                                          const float* __restrict__ c0in,
                                          u16* h0buf, u16* h1buf, u16* h1fin,
                                          u32* cnt, int wg, char* smem) {
    constexpr int LA = 7;                  // A lookahead (8-slot ring)
    const int tid = threadIdx.x;
    const int wid = tid >> 6, lane = tid & 63;
    const int ks = wid & 3, nt = (wid >> 2) & 1, cg = wid >> 3;
    const int ln15 = lane & 15, lhi = lane >> 4;
    const int vg = wg * 2 + cg;            // 8-col group index in [0,128)
    const int col0 = wg * 16;
    const int m_u = tid & 63, cp_u = (tid >> 6) & 7;  // cell update (tid<512 active)
    int dead = 0;
    float* Pf = (float*)smem;              // epilogue overlay (ring slots 0-3, 64 KB)
    u32* hstg = (u32*)(smem + 65536);      // epilogue overlay (slot 4 head, 2 KB)
    u32* slotp = cnt + (LAYER == 0 ? 0 : 128) + (wg & 7) * 16;

    // ---- one-time: resident weights, NC frags (frag 2c+nt of stream vg*4+ks)
    const u16* wbase = Wpk + ((size_t)(vg * 4 + ks) * (2 * NC) + nt) * 512 + lane * 8;
    s16x8 wfr[NC];
    sfor<NC>([&](auto cc) { wfr[cc.v] = ldg_pin(wbase + (size_t)cc.v * 1024); });
    waitvm0();

    // staging geometry: wave stages rows wid*4 + lhi, k-block ln15 (1 KB/wave/chunk)
    const int srow = wid * 4 + lhi;
    const int xoff = srow * 1024 + ((ln15 ^ (srow & 7)) << 4);    // x: logical->swizzled
    const int wib = wid * 1024 + lane * 16;                        // h: pre-swizzled linear

    float bR[4][2];
#pragma unroll
    for (int g = 0; g < 4; ++g) {
        bR[g][0] = bias[g * 1024 + col0 + cp_u * 2 + 0];
        bR[g][1] = bias[g * 1024 + col0 + cp_u * 2 + 1];
    }
    float cr0 = c0in[(size_t)m_u * 1024 + col0 + cp_u * 2 + 0];
    float cr1 = c0in[(size_t)m_u * 1024 + col0 + cp_u * 2 + 1];

    for (int p = 0; p < Sn; ++p) {
        // ---- dependency wait (decoupled)
        if constexpr (LAYER == 0) {
            const u32 tgt0 = (p >= 1) ? 64u * (u32)p : 0u;          // own prev phase done
            const u32 tgt1 = (p >= 4) ? 64u * (u32)(p - 3) : 0u;    // L1 freed slab p&3
            waitcnts(cnt, tgt0, tgt1, dead);
        } else {
            const u32 tgt0 = 64u * (u32)(p + 1);                    // h0[p] complete
            const u32 tgt1 = (p >= 1) ? 64u * (u32)p : 0u;          // own prev phase done
            waitcnts(cnt, tgt0, tgt1, dead);
        }

        const char* hA;
        const char* hB = nullptr;
        u16* hw;
        const char* xsl = nullptr;
        if constexpr (LAYER == 0) {
            hA = (const char*)h0buf + (size_t)((p - 1) & 3) * SLAB;   // h0[p-1]
            hw = (u16*)((char*)h0buf + (size_t)(p & 3) * SLAB);       // h0[p]
            xsl = (const char*)xpk + (size_t)p * 65536;
        } else {
            hA = (const char*)h0buf + (size_t)(p & 3) * SLAB;         // h0[p]
            hB = (const char*)h1buf + (size_t)((p - 1) & 1) * SLAB;   // h1[p-1]
            hw = (u16*)((char*)h1buf + (size_t)(p & 1) * SLAB);       // h1[p]
        }

        auto issueA = [&](auto cc) {
            constexpr int c = cc.v;
            char* dst = smem + ((c & 7) << 14) + wid * 1024;   // wave-uniform
            if constexpr (LAYER == 0 && c < XC) {
                dmaA(xsl + xoff + c * 256, dst);
            } else if constexpr (LAYER == 0) {
                dmaAcoh(hA + ((c - XC) << 14) + wib, dst);
            } else if constexpr (c < XC) {
                dmaAcoh(hA + (c << 14) + wib, dst);
            } else {
                dmaAcoh(hB + ((c - XC) << 14) + wib, dst);
            }
        };

        // prologue: A chunks 0..LA-1 into slots 0..6
        sfor<LA>([&](auto k) { issueA(k); });

        f32x4 acc[4];
#pragma unroll
        for (int mi = 0; mi < 4; ++mi) acc[mi] = f32x4{0.f, 0.f, 0.f, 0.f};

        sfor<NC>([&](auto cc) {
            constexpr int c = cc.v;
            constexpr int W = (LA - 1 < NC - 1 - c) ? LA - 1 : NC - 1 - c;
            waitvmN<W>();                          // own chunk-c DMA done (A-only FIFO)
            __builtin_amdgcn_s_barrier();          // all waves' chunk-c staged;
            __builtin_amdgcn_sched_barrier(0);     //  slot (c-1)&7 free for overwrite
            if constexpr (c + LA < NC) issueA(IC<c + LA>{});
            const int ab = (c & 7) << 14;
#pragma unroll
            for (int mi = 0; mi < 4; ++mi) {
                const int arow = mi * 16 + ln15;
                const s16x8 af =
                    *(const s16x8*)&smem[ab + arow * 256 + (((ks * 4 + lhi) ^ (arow & 7)) << 4)];
                acc[mi] = __builtin_amdgcn_mfma_f32_16x16x32_bf16(af, wfr[c], acc[mi], 0, 0, 0);
            }
        });

        // ---- epilogue: cross-wave reduction (Pf overlays ring slots 0-3 -> sync first)
        __syncthreads();
#pragma unroll
        for (int mi = 0; mi < 4; ++mi)
#pragma unroll
            for (int r = 0; r < 4; ++r) {
                const int row = cg * 128 + ks * 32 + (nt * 2 + (ln15 >> 3)) * 8 + (ln15 & 7);
                const int m = mi * 16 + lhi * 4 + r;
                Pf[PFI(row, m)] = acc[mi][r];
            }
        __syncthreads();

        if (tid < 512) {   // fused cell update: thread owns (m_u, cols col0+2cp_u..+1)
            float sg[4][2];
#pragma unroll
            for (int g = 0; g < 4; ++g) { sg[g][0] = bR[g][0]; sg[g][1] = bR[g][1]; }
#pragma unroll
            for (int j = 0; j < 2; ++j) {
                const int ci = cp_u * 2 + j;
                const int cgj = ci >> 3, colw = ci & 7;
#pragma unroll
                for (int k2 = 0; k2 < 4; ++k2)
#pragma unroll
                    for (int g = 0; g < 4; ++g)
                        sg[g][j] += Pf[PFI(cgj * 128 + k2 * 32 + g * 8 + colw, m_u)];
            }
            const float i0 = sigmf(sg[0][0]), f0 = sigmf(sg[1][0]), g0 = tanhf(sg[2][0]), o0 = sigmf(sg[3][0]);
            const float i1 = sigmf(sg[0][1]), f1 = sigmf(sg[1][1]), g1 = tanhf(sg[2][1]), o1 = sigmf(sg[3][1]);
            cr0 = f0 * cr0 + i0 * g0;
            cr1 = f1 * cr1 + i1 * g1;
            const u16 hb0 = f2bf(o0 * tanhf(cr0));
            const u16 hb1 = f2bf(o1 * tanhf(cr1));
            hstg[m_u * 8 + cp_u] = (u32)hb0 | ((u32)hb1 << 16);
        }
        __syncthreads();
        if (tid < 128) {   // one coherent 16B store per (row, 8-col half)
            const int r = tid >> 1, half = tid & 1;
            u32x4 hv;
            hv[0] = hstg[r * 8 + half * 4 + 0]; hv[1] = hstg[r * 8 + half * 4 + 1];
            hv[2] = hstg[r * 8 + half * 4 + 2]; hv[3] = hstg[r * 8 + half * 4 + 3];
            if (LAYER == 1 && p == Sn - 1) {
                stg_coh128(&h1fin[(size_t)r * Hn + col0 + half * 8], hv);  // plain for FC
            } else {
                const int cb = wg * 2 + half;          // block index in [0,128)
                const int ck = cb >> 4, bl = cb & 15;
                stg_coh128(hw + ck * 8192 + (r * 16 + (bl ^ (r & 7))) * 8, hv);
            }
        }
        arrive(slotp, dead);   // stores acked -> signal this group's counter
    }
    waitvm0();
}

__global__ __attribute__((amdgpu_flat_work_group_size(1024, 1024)))
void lstm_persist(const u16* __restrict__ xpk,
                  const u16* __restrict__ Wpk0,
                  const u16* __restrict__ Wpk1,
                  const float* __restrict__ bias,
                  const float* __restrict__ c0in,
                  u16* h0buf, u16* h1buf, u16* h1fin, u32* cnt) {
    __shared__ __align__(16) char smem[131072];   // 8-slot A ring; 1 WG/CU
    if (blockIdx.x < 64)
        run_layer<12, 4, 0>(xpk, Wpk0, bias, c0in, h0buf, h1buf, h1fin, cnt, blockIdx.x, smem);
    else
        run_layer<16, 8, 1>(xpk, Wpk1, bias + 4096, c0in + BH, h0buf, h1buf, h1fin, cnt,
                            blockIdx.x - 64, smem);
}

// ---------------- final FC + sigmoid ----------------
__global__ __launch_bounds__(256) void fc_out(const u16* __restrict__ h1,
                                              const float* __restrict__ fcW,
                                              const float* __restrict__ fcb,
                                              float* __restrict__ out) {
    const int b = blockIdx.x;  // 64
    __shared__ float hs[Hn];
    for (int k = threadIdx.x; k < Hn; k += 256) hs[k] = bf2f(h1[(size_t)b * Hn + k]);
    __syncthreads();
    const int o = threadIdx.x;  // 256
    float acc = fcb[o];
    const float4* wr = (const float4*)(fcW + (size_t)o * Hn);
    const float4* hv = (const float4*)hs;
#pragma unroll 8
    for (int k4 = 0; k4 < Hn / 4; ++k4) {
        const float4 w = wr[k4];
        const float4 h = hv[k4];
        acc += w.x * h.x + w.y * h.y + w.z * h.z + w.w * h.w;
    }
    out[(size_t)b * On + o] = sigmf(acc);
}

extern "C" void kernel_launch(void* const* d_in, const int* in_sizes, int n_in,
                              void* d_out, int out_size, void* d_ws, size_t ws_size,
                              hipStream_t stream) {
    (void)in_sizes; (void)n_in; (void)out_size; (void)ws_size;
    const float* x   = (const float*)d_in[0];
    const float* h0i = (const float*)d_in[1];
    const float* c0i = (const float*)d_in[2];
    const float* Wx0 = (const float*)d_in[3];
    const float* Wh0 = (const float*)d_in[4];
    const float* bx0 = (const float*)d_in[5];
    const float* bh0 = (const float*)d_in[6];
    const float* Wx1 = (const float*)d_in[7];
    const float* Wh1 = (const float*)d_in[8];
    const float* bx1 = (const float*)d_in[9];
    const float* bh1 = (const float*)d_in[10];
    const float* fcW = (const float*)d_in[11];
    const float* fcb = (const float*)d_in[12];
    float* out = (float*)d_out;

    char* ws = (char*)d_ws;
    u16* Wpk0   = (u16*)(ws + 0);            // 12,582,912 B
    u16* Wpk1   = (u16*)(ws + 12582912);     // 16,777,216 B
    u16* xpk    = (u16*)(ws + 29360128);     // 33,554,432 B  [t][b][d] bf16
    float* bias = (float*)(ws + 62914560);   // 32,768 B
    u16* h0buf  = (u16*)(ws + 62947328);     // 524,288 B (4 swizzled slabs)
    u16* h1buf  = (u16*)(ws + 63471616);     // 262,144 B (2 swizzled slabs)
    u16* h1fin  = (u16*)(ws + 63733760);     // 131,072 B (plain, for FC)
    u32* cnt    = (u32*)(ws + 63864832);     // 1,024 B (16 split counters)

    prep_kernel<<<2048, 256, 0, stream>>>(Wx0, Wh0, bx0, bh0, Wx1, Wh1, bx1, bh1,
                                          h0i, x, Wpk0, Wpk1, xpk, bias, h0buf, h1buf, cnt);

    lstm_persist<<<128, 1024, 0, stream>>>(xpk, Wpk0, Wpk1, bias, c0i, h0buf, h1buf, h1fin, cnt);

    fc_out<<<64, 256, 0, stream>>>(h1fin, fcW, fcb, out);
}